// Round 4
// baseline (3860.306 us; speedup 1.0000x reference)
//
#include <hip/hip_runtime.h>
#include <math.h>

// RBF_Conv2d cdist: x (B,3,224,224) f32, weight (64,75) f32 -> out (B,64,224,224) f32
// dist[b,o,y,x] = || window(b,:,y,x) - weight[o,:] ||_2
//
// Single self-contained kernel (no workspace, no inter-kernel dependency --
// round 3 failed post-timing revalidation, suspect ws-visibility race class).
// Register budget kept ~64 VGPR so default occupancy allocation has no spills:
//   - o-tile of 16 accumulators (static unrolled indexing)
//   - window values re-streamed from L1 per tile (25x spatial reuse, cheap)
//   - weight reads wave-uniform -> s_load on the scalar pipe
//   - ||w||^2 computed once per block into LDS

#define KH 5
#define KW 5
#define PAD 2
#define CH 3
#define DD 75          // CH*KH*KW
#define OC 64
#define HH 224
#define WW 224
#define HW (HH * WW)
#define OTILE 16

__global__ __launch_bounds__(256) void rbf_kernel(const float* __restrict__ x,
                                                  const float* __restrict__ w,
                                                  float* __restrict__ out) {
    __shared__ float wn_s[OC];
    int tid = threadIdx.x;

    // Per-block ||w_o||^2 (19KB of w reads, L2/L3-hot across blocks).
    if (tid < OC) {
        const float* wr = w + tid * DD;
        float s = 0.f;
#pragma unroll 5
        for (int d = 0; d < DD; ++d) s = fmaf(wr[d], wr[d], s);
        wn_s[tid] = s;
    }
    __syncthreads();

    int p  = blockIdx.x * 256 + tid;   // pixel id; grid sized exactly
    int xc = p % WW;
    int t  = p / WW;
    int yc = t % HH;
    int b  = t / HH;

    const float* xb = x + (size_t)b * (CH * HW);

    // Precompute clamped row bases / x offsets / validity once.
    int  rbase[CH * KH];
    bool yval[KH];
#pragma unroll
    for (int i = 0; i < KH; ++i) {
        int yy   = yc + i - PAD;
        yval[i]  = (unsigned)yy < (unsigned)HH;
        int ycl  = min(max(yy, 0), HH - 1);
#pragma unroll
        for (int c = 0; c < CH; ++c) rbase[c * KH + i] = (c * HH + ycl) * WW;
    }
    int  xoff[KW];
    bool xval[KW];
#pragma unroll
    for (int j = 0; j < KW; ++j) {
        int xx  = xc + j - PAD;
        xval[j] = (unsigned)xx < (unsigned)WW;
        xoff[j] = min(max(xx, 0), WW - 1);
    }

    // pn pre-pass (also warms L1 for the tile loops).
    float pn = 0.f;
#pragma unroll
    for (int c = 0; c < CH; ++c)
#pragma unroll
        for (int i = 0; i < KH; ++i) {
            int rb = rbase[c * KH + i];
#pragma unroll
            for (int j = 0; j < KW; ++j) {
                float v = xb[rb + xoff[j]];
                v = (yval[i] && xval[j]) ? v : 0.f;
                pn = fmaf(v, v, pn);
            }
        }

    float* ob = out + ((size_t)b * OC) * HW + (size_t)(yc * WW + xc);

    // 4 o-tiles of 16; window streamed from L1 each tile, weights via s_load.
#pragma unroll 1
    for (int og = 0; og < OC; og += OTILE) {
        const float* wo = w + og * DD;          // wave-uniform base
        float acc[OTILE];
#pragma unroll
        for (int oo = 0; oo < OTILE; ++oo) acc[oo] = 0.f;

#pragma unroll
        for (int c = 0; c < CH; ++c)
#pragma unroll
            for (int i = 0; i < KH; ++i) {
                int rb = rbase[c * KH + i];
#pragma unroll
                for (int j = 0; j < KW; ++j) {
                    float v = xb[rb + xoff[j]];
                    v = (yval[i] && xval[j]) ? v : 0.f;
                    int d = (c * KH + i) * KW + j;
#pragma unroll
                    for (int oo = 0; oo < OTILE; ++oo)
                        acc[oo] = fmaf(v, wo[oo * DD + d], acc[oo]);
                }
            }

#pragma unroll
        for (int oo = 0; oo < OTILE; ++oo) {
            float d2 = fmaf(-2.f, acc[oo], pn + wn_s[og + oo]);
            ob[(size_t)(og + oo) * HW] = sqrtf(fmaxf(d2, 0.f));
        }
    }
}

extern "C" void kernel_launch(void* const* d_in, const int* in_sizes, int n_in,
                              void* d_out, int out_size, void* d_ws, size_t ws_size,
                              hipStream_t stream) {
    const float* x = (const float*)d_in[0];
    const float* w = (const float*)d_in[1];
    float* out     = (float*)d_out;

    int B    = in_sizes[0] / (CH * HW);   // 32
    int npix = B * HW;                    // 1,605,632 (divisible by 256)

    rbf_kernel<<<npix / 256, 256, 0, stream>>>(x, w, out);
}

// Round 5
// 209.959 us; speedup vs baseline: 18.3860x; 18.3860x over previous
//
#include <hip/hip_runtime.h>
#include <hip/hip_bf16.h>
#include <math.h>

// RBF_Conv2d cdist via MFMA implicit GEMM.
// out[b,o,y,x] = sqrt(max(pn[b,y,x] + wn[o] - 2*dot(win,w_o), 0))
// GEMM: C[o][p] = sum_d (-2*w[o][d]) * X[d][p] with mfma_f32_32x32x16_bf16.
// Wave = one 32-pixel row strip x all 64 outputs. B-frags built in registers
// from coalesced global loads (lane's k-octet == the 8 values it loads).
// Precision: x and w split into bf16 hi+lo, 3 MFMA products -> ~f32 dot.

#define KH 5
#define KW 5
#define PAD 2
#define CH 3
#define DD 75
#define OC 64
#define HH 224
#define WW 224
#define HW (HH * WW)
#define NSX 7            // 224/32 strips per row

using short8_t = __attribute__((ext_vector_type(8))) short;
using f32x16   = __attribute__((ext_vector_type(16))) float;

__device__ inline unsigned short bf16_bits(float v) {
    __hip_bfloat16 h = __float2bfloat16(v);          // RNE hw cvt
    return __builtin_bit_cast(unsigned short, h);
}
__device__ inline float bf16_val(unsigned short u) {
    return __builtin_bit_cast(float, (unsigned)u << 16);
}

// Build one window k-octet (8 consecutive d starting at D0) for this lane's
// pixel column. Compile-time (c,i,j) per element; OOB -> 0.
template<int D0>
__device__ inline void build_b(const float* __restrict__ xb, int y, int xp,
                               float& pn, short8_t& bh, short8_t& bl) {
#pragma unroll
    for (int r = 0; r < 8; ++r) {
        const int d = D0 + r;
        float v = 0.f;
        if (d < DD) {
            const int c = d / 25, rem = d % 25, i = rem / 5, j = rem % 5;
            int gy = y + i - PAD;
            int gx = xp + j;
            bool ok = ((unsigned)gy < (unsigned)HH) && ((unsigned)gx < (unsigned)WW);
            int gyc = min(max(gy, 0), HH - 1);
            int gxc = min(max(gx, 0), WW - 1);
            float raw = xb[(c * HH + gyc) * WW + gxc];
            v = ok ? raw : 0.f;
        }
        pn = fmaf(v, v, pn);
        unsigned short hb = bf16_bits(v);
        float hf = bf16_val(hb);
        unsigned short lb = bf16_bits(v - hf);
        bh[r] = (short)hb;
        bl[r] = (short)lb;
    }
}

// Build one weight k-octet for output row o (value = -2*w[o][d], hi/lo split).
template<int D0>
__device__ inline void build_a(const float* __restrict__ w, int o,
                               short8_t& ah, short8_t& al) {
#pragma unroll
    for (int r = 0; r < 8; ++r) {
        const int d = D0 + r;
        float v = (d < DD) ? (-2.f * w[o * DD + d]) : 0.f;
        unsigned short hb = bf16_bits(v);
        float hf = bf16_val(hb);
        unsigned short lb = bf16_bits(v - hf);
        ah[r] = (short)hb;
        al[r] = (short)lb;
    }
}

__global__ __launch_bounds__(256, 2) void rbf_mfma(const float* __restrict__ x,
                                                   const float* __restrict__ w,
                                                   float* __restrict__ out,
                                                   int nstrips, int nwaves) {
    __shared__ float wn_s[OC];
    const int tid = threadIdx.x;
    if (tid < OC) {
        const float* wr = w + tid * DD;
        float s = 0.f;
#pragma unroll 5
        for (int d = 0; d < DD; ++d) s = fmaf(wr[d], wr[d], s);
        wn_s[tid] = s;
    }
    __syncthreads();

    const int lane = tid & 63;
    const int wid  = tid >> 6;
    const int l31  = lane & 31;   // A-row (o) / B-col (pixel) owned by lane
    const int hi   = lane >> 5;   // which k-octet of each K=16 step

    // Preload A fragments (weights) once; amortized over the strip loop.
    short8_t ah[2][5], al[2][5];
    if (hi == 0) {
#pragma unroll
        for (int mt = 0; mt < 2; ++mt) {
            build_a<0 >(w, l31 + 32 * mt, ah[mt][0], al[mt][0]);
            build_a<16>(w, l31 + 32 * mt, ah[mt][1], al[mt][1]);
            build_a<32>(w, l31 + 32 * mt, ah[mt][2], al[mt][2]);
            build_a<48>(w, l31 + 32 * mt, ah[mt][3], al[mt][3]);
            build_a<64>(w, l31 + 32 * mt, ah[mt][4], al[mt][4]);
        }
    } else {
#pragma unroll
        for (int mt = 0; mt < 2; ++mt) {
            build_a<8 >(w, l31 + 32 * mt, ah[mt][0], al[mt][0]);
            build_a<24>(w, l31 + 32 * mt, ah[mt][1], al[mt][1]);
            build_a<40>(w, l31 + 32 * mt, ah[mt][2], al[mt][2]);
            build_a<56>(w, l31 + 32 * mt, ah[mt][3], al[mt][3]);
            build_a<72>(w, l31 + 32 * mt, ah[mt][4], al[mt][4]);
        }
    }

    const int gw = blockIdx.x * 4 + wid;
    for (int s = gw; s < nstrips; s += nwaves) {
        const int x0 = (s % NSX) * 32;
        const int t  = s / NSX;
        const int y  = t % HH;
        const int b  = t / HH;
        const float* xb = x + (size_t)b * (CH * HW);
        const int xp = x0 + l31 - PAD;

        float pnp = 0.f;
        short8_t bh[5], bl[5];
        if (hi == 0) {
            build_b<0 >(xb, y, xp, pnp, bh[0], bl[0]);
            build_b<16>(xb, y, xp, pnp, bh[1], bl[1]);
            build_b<32>(xb, y, xp, pnp, bh[2], bl[2]);
            build_b<48>(xb, y, xp, pnp, bh[3], bl[3]);
            build_b<64>(xb, y, xp, pnp, bh[4], bl[4]);
        } else {
            build_b<8 >(xb, y, xp, pnp, bh[0], bl[0]);
            build_b<24>(xb, y, xp, pnp, bh[1], bl[1]);
            build_b<40>(xb, y, xp, pnp, bh[2], bl[2]);
            build_b<56>(xb, y, xp, pnp, bh[3], bl[3]);
            build_b<72>(xb, y, xp, pnp, bh[4], bl[4]);
        }

        f32x16 acc0 = {0.f, 0.f, 0.f, 0.f, 0.f, 0.f, 0.f, 0.f,
                       0.f, 0.f, 0.f, 0.f, 0.f, 0.f, 0.f, 0.f};
        f32x16 acc1 = acc0;
#pragma unroll
        for (int st = 0; st < 5; ++st) {
            acc0 = __builtin_amdgcn_mfma_f32_32x32x16_bf16(ah[0][st], bh[st], acc0, 0, 0, 0);
            acc1 = __builtin_amdgcn_mfma_f32_32x32x16_bf16(ah[1][st], bh[st], acc1, 0, 0, 0);
            acc0 = __builtin_amdgcn_mfma_f32_32x32x16_bf16(ah[0][st], bl[st], acc0, 0, 0, 0);
            acc1 = __builtin_amdgcn_mfma_f32_32x32x16_bf16(ah[1][st], bl[st], acc1, 0, 0, 0);
            acc0 = __builtin_amdgcn_mfma_f32_32x32x16_bf16(al[0][st], bh[st], acc0, 0, 0, 0);
            acc1 = __builtin_amdgcn_mfma_f32_32x32x16_bf16(al[1][st], bh[st], acc1, 0, 0, 0);
        }

        // full ||p||^2: this lane holds half the d's, partner lane (xor 32) the rest
        float pn = pnp + __shfl_xor(pnp, 32);

        float* op = out + ((size_t)b * OC) * HW + (size_t)(y * WW + x0 + l31);
        // C/D layout (verified m74/m101): col = lane&31, row = (reg&3)+8*(reg>>2)+4*(lane>>5)
#pragma unroll
        for (int reg = 0; reg < 16; ++reg) {
            const int o31 = (reg & 3) + 8 * (reg >> 2) + 4 * hi;
            float d2a = pn + wn_s[o31] + acc0[reg];
            op[(size_t)o31 * HW] = sqrtf(fmaxf(d2a, 0.f));
            float d2b = pn + wn_s[o31 + 32] + acc1[reg];
            op[(size_t)(o31 + 32) * HW] = sqrtf(fmaxf(d2b, 0.f));
        }
    }
}

extern "C" void kernel_launch(void* const* d_in, const int* in_sizes, int n_in,
                              void* d_out, int out_size, void* d_ws, size_t ws_size,
                              hipStream_t stream) {
    const float* x = (const float*)d_in[0];
    const float* w = (const float*)d_in[1];
    float* out     = (float*)d_out;

    int B       = in_sizes[0] / (CH * HW);   // 32
    int nstrips = B * HH * NSX;              // 50176
    int nblocks = 1024;
    int nwaves  = nblocks * 4;

    rbf_mfma<<<nblocks, 256, 0, stream>>>(x, w, out, nstrips, nwaves);
}

// Round 7
// 178.300 us; speedup vs baseline: 21.6506x; 1.1776x over previous
//
#include <hip/hip_runtime.h>
#include <hip/hip_bf16.h>
#include <math.h>

// RBF_Conv2d cdist via MFMA implicit GEMM (round 7 = round 6 + compile fix).
// acc = sum_d A[o][d]*B[d][p] over padded K=80 where
//   d<75 : A = -2*w (bf16 RNE), B = x split hi(trunc)+lo(bf16 of residual), 2 products
//   d=75 : A = wn_hi,  B = {1,0}   d=76 : A = wn_lo, B = {1,0}
//   d=77 : A = 1.0,    B = {pn_hi, pn_lo}
// so acc == d2 = pn + wn - 2*dot directly; epilogue = sqrt(max(acc,0)).

#define KH 5
#define KW 5
#define PAD 2
#define CH 3
#define DD 75
#define OC 64
#define HH 224
#define WW 224
#define HW (HH * WW)
#define NSX 7            // 224/32 strips per row

using short8_t = __attribute__((ext_vector_type(8))) short;
using f32x16   = __attribute__((ext_vector_type(16))) float;

union Oct { unsigned int w[4]; short8_t v; };

__device__ inline unsigned int rne_bf16(float v) {
    return (unsigned int)__builtin_bit_cast(unsigned short, __float2bfloat16(v));
}

// window element value; d is constant after unroll+inline -> all math folds.
template<bool EDGE>
__device__ inline float xelem(const float* __restrict__ xb, int y, int xp, int d) {
    if (d >= DD) return 0.f;
    const int c = d / 25, rem = d % 25, i = rem / 5, j = rem % 5;
    int gy = y + i - PAD;
    int gx = xp + j;
    if constexpr (!EDGE) {
        return xb[(c * HH + gy) * WW + gx];
    } else {
        bool ok = ((unsigned)gy < (unsigned)HH) & ((unsigned)gx < (unsigned)WW);
        int gyc = min(max(gy, 0), HH - 1);
        int gxc = min(max(gx, 0), WW - 1);
        float raw = xb[(c * HH + gyc) * WW + gxc];
        return ok ? raw : 0.f;
    }
}

template<int D0, bool EDGE>
__device__ inline void build_oct(const float* __restrict__ xb, int y, int xp,
                                 float& pn, Oct& bh, Oct& bl) {
#pragma unroll
    for (int rr = 0; rr < 8; rr += 2) {
        float v0 = xelem<EDGE>(xb, y, xp, D0 + rr);
        float v1 = xelem<EDGE>(xb, y, xp, D0 + rr + 1);
        pn = fmaf(v0, v0, pn);
        pn = fmaf(v1, v1, pn);
        unsigned int u0 = __builtin_bit_cast(unsigned int, v0);
        unsigned int u1 = __builtin_bit_cast(unsigned int, v1);
        bh.w[rr >> 1] = (u0 >> 16) | (u1 & 0xFFFF0000u);      // packed trunc-hi
        float h0 = __builtin_bit_cast(float, u0 & 0xFFFF0000u);
        float h1 = __builtin_bit_cast(float, u1 & 0xFFFF0000u);
        bl.w[rr >> 1] = rne_bf16(v0 - h0) | (rne_bf16(v1 - h1) << 16);
    }
}

template<int D0>
__device__ inline void build_aoct(const float* __restrict__ wrow, Oct& a) {
#pragma unroll
    for (int rr = 0; rr < 8; rr += 2) {
        float v0 = (D0 + rr     < DD) ? (-2.f * wrow[D0 + rr])     : 0.f;
        float v1 = (D0 + rr + 1 < DD) ? (-2.f * wrow[D0 + rr + 1]) : 0.f;
        a.w[rr >> 1] = rne_bf16(v0) | (rne_bf16(v1) << 16);
    }
}

template<bool EDGE>
__device__ inline void do_strip(const float* __restrict__ xb, int y, int xp, int hi,
                                const Oct (&ah)[2][5], float* __restrict__ op) {
    float pnp = 0.f;
    Oct bh[5], bl[5];
    if (hi == 0) {
        build_oct<0,  EDGE>(xb, y, xp, pnp, bh[0], bl[0]);
        build_oct<16, EDGE>(xb, y, xp, pnp, bh[1], bl[1]);
        build_oct<32, EDGE>(xb, y, xp, pnp, bh[2], bl[2]);
        build_oct<48, EDGE>(xb, y, xp, pnp, bh[3], bl[3]);
        build_oct<64, EDGE>(xb, y, xp, pnp, bh[4], bl[4]);
    } else {
        build_oct<8,  EDGE>(xb, y, xp, pnp, bh[0], bl[0]);
        build_oct<24, EDGE>(xb, y, xp, pnp, bh[1], bl[1]);
        build_oct<40, EDGE>(xb, y, xp, pnp, bh[2], bl[2]);
        build_oct<56, EDGE>(xb, y, xp, pnp, bh[3], bl[3]);
        build_oct<72, EDGE>(xb, y, xp, pnp, bh[4], bl[4]);
    }
    float pn = pnp + __shfl_xor(pnp, 32);   // partner half-wave holds the other d's
    if (hi == 1) {
        // pad slots d75..d77 live in hi=1's step-4 octet (elements 3,4,5)
        unsigned int up  = __builtin_bit_cast(unsigned int, pn);
        unsigned int pnh = up >> 16;
        float pnhv = __builtin_bit_cast(float, up & 0xFFFF0000u);
        unsigned int pnl = rne_bf16(pn - pnhv);
        bh[4].w[1] |= 0x3F800000u;                 // elem3 (d75): 1.0
        bh[4].w[2]  = 0x3F80u | (pnh << 16);       // elem4 (d76): 1.0, elem5 (d77): pn_hi
        bl[4].w[2]  = (pnl << 16);                 // elem5 lo-product: pn_lo
    }

    f32x16 acc0 = {0.f,0.f,0.f,0.f,0.f,0.f,0.f,0.f,0.f,0.f,0.f,0.f,0.f,0.f,0.f,0.f};
    f32x16 acc1 = acc0;
#pragma unroll
    for (int st = 0; st < 5; ++st) {
        acc0 = __builtin_amdgcn_mfma_f32_32x32x16_bf16(ah[0][st].v, bh[st].v, acc0, 0, 0, 0);
        acc1 = __builtin_amdgcn_mfma_f32_32x32x16_bf16(ah[1][st].v, bh[st].v, acc1, 0, 0, 0);
        acc0 = __builtin_amdgcn_mfma_f32_32x32x16_bf16(ah[0][st].v, bl[st].v, acc0, 0, 0, 0);
        acc1 = __builtin_amdgcn_mfma_f32_32x32x16_bf16(ah[1][st].v, bl[st].v, acc1, 0, 0, 0);
    }

    // C/D layout: col = lane&31 (pixel), row = (reg&3)+8*(reg>>2)+4*hi (+32 for acc1);
    // the +4*hi is folded into op by the caller.
#pragma unroll
    for (int reg = 0; reg < 16; ++reg) {
        int ob = (reg & 3) + 8 * (reg >> 2);
        op[(size_t)ob * HW]        = sqrtf(fmaxf(acc0[reg], 0.f));
        op[(size_t)(ob + 32) * HW] = sqrtf(fmaxf(acc1[reg], 0.f));
    }
}

__global__ __launch_bounds__(256, 3) void rbf_mfma(const float* __restrict__ x,
                                                   const float* __restrict__ w,
                                                   float* __restrict__ out,
                                                   int nstrips, int nwaves) {
    const int tid  = threadIdx.x;
    const int lane = tid & 63;
    const int l31  = lane & 31;
    const int hi   = lane >> 5;

    // ---- one-time A-fragment + wn build (amortized over ~16 strips) ----
    float wn[2];
#pragma unroll
    for (int mt = 0; mt < 2; ++mt) {
        const float* wrow = w + (l31 + 32 * mt) * DD;
        float s = 0.f;
#pragma unroll 5
        for (int d = 0; d < DD; ++d) { float v = wrow[d]; s = fmaf(v, v, s); }
        wn[mt] = s;
    }
    Oct ah[2][5];
    if (hi == 0) {
#pragma unroll
        for (int mt = 0; mt < 2; ++mt) {
            const float* wrow = w + (l31 + 32 * mt) * DD;
            build_aoct<0 >(wrow, ah[mt][0]);
            build_aoct<16>(wrow, ah[mt][1]);
            build_aoct<32>(wrow, ah[mt][2]);
            build_aoct<48>(wrow, ah[mt][3]);
            build_aoct<64>(wrow, ah[mt][4]);
        }
    } else {
#pragma unroll
        for (int mt = 0; mt < 2; ++mt) {
            const float* wrow = w + (l31 + 32 * mt) * DD;
            build_aoct<8 >(wrow, ah[mt][0]);
            build_aoct<24>(wrow, ah[mt][1]);
            build_aoct<40>(wrow, ah[mt][2]);
            build_aoct<56>(wrow, ah[mt][3]);
            build_aoct<72>(wrow, ah[mt][4]);
            // pad slots d75,d76 = wn hi/lo ; d77 = 1.0 (multiplies pn)
            unsigned int uwn = __builtin_bit_cast(unsigned int, wn[mt]);
            unsigned int wnh = uwn >> 16;
            float wnhv = __builtin_bit_cast(float, uwn & 0xFFFF0000u);
            unsigned int wnl = rne_bf16(wn[mt] - wnhv);
            ah[mt][4].w[1] = (ah[mt][4].w[1] & 0xFFFFu) | (wnh << 16);  // elem3: wn_hi
            ah[mt][4].w[2] = wnl | (0x3F80u << 16);                     // elem4: wn_lo, elem5: 1.0
            ah[mt][4].w[3] = 0u;
        }
    }

    // ---- strip loop ----
    const int gw = blockIdx.x * 4 + (tid >> 6);
    for (int s = gw; s < nstrips; s += nwaves) {
        int sx = s % NSX;
        int t  = s / NSX;
        int y  = t % HH;
        int b  = t / HH;
        int x0 = sx * 32;
        const float* xb = x + (size_t)b * (CH * HW);
        int xp = x0 + l31 - PAD;
        float* op = out + (size_t)b * OC * HW + (size_t)(y * WW + x0 + l31)
                        + (size_t)hi * 4 * HW;
        bool interior = (y >= PAD) & (y < HH - PAD) & (sx >= 1) & (sx <= 5);
        if (interior) do_strip<false>(xb, y, xp, hi, ah, op);
        else          do_strip<true >(xb, y, xp, hi, ah, op);
    }
}

extern "C" void kernel_launch(void* const* d_in, const int* in_sizes, int n_in,
                              void* d_out, int out_size, void* d_ws, size_t ws_size,
                              hipStream_t stream) {
    const float* x = (const float*)d_in[0];
    const float* w = (const float*)d_in[1];
    float* out     = (float*)d_out;

    int B       = in_sizes[0] / (CH * HW);   // 32
    int nstrips = B * HH * NSX;              // 50176
    int nblocks = 768;                       // 3 blocks/CU exactly
    int nwaves  = nblocks * 4;

    rbf_mfma<<<nblocks, 256, 0, stream>>>(x, w, out, nstrips, nwaves);
}

// Round 9
// 164.809 us; speedup vs baseline: 23.4228x; 1.0819x over previous
//
#include <hip/hip_runtime.h>
#include <hip/hip_bf16.h>
#include <math.h>

// RBF_Conv2d cdist via MFMA implicit GEMM (round 9).
// acc = sum_d A[o][d]*B[d][p] over padded K=80:
//   d<75 : A = bf16(-2*w), B = bf16_rne(x)          (single product)
//   d=75 : A = wn_hi, B = 1.0     d=76 : A = wn_lo, B = 1.0
//   d=77 : A = 1.0,   B = pn_hi   d=78 : A = 1.0,   B = pn_lo
// so acc == d2 = pn + wn - 2*dot; epilogue = sqrt(max(acc,0)).
// CORRECTNESS RULE (round-8 lesson): MFMA operands are wave-collective --
// builds may be lane-divergent, but every MFMA must issue after
// re-convergence, when ALL 64 lanes' B registers hold their octet.

#define KH 5
#define KW 5
#define PAD 2
#define CH 3
#define DD 75
#define OC 64
#define HH 224
#define WW 224
#define HW (HH * WW)
#define NSX 7            // 224/32 strips per row

using short8_t = __attribute__((ext_vector_type(8))) short;
using f32x16   = __attribute__((ext_vector_type(16))) float;

union Oct { unsigned int w[4]; short8_t v; };

__device__ inline unsigned int rne_bf16(float v) {
    return (unsigned int)__builtin_bit_cast(unsigned short, __float2bfloat16(v));
}

// window element value; d is constant after unroll+inline -> all math folds.
template<bool EDGE>
__device__ inline float xelem(const float* __restrict__ xb, int y, int xp, int d) {
    if (d >= DD) return 0.f;
    const int c = d / 25, rem = d % 25, i = rem / 5, j = rem % 5;
    int gy = y + i - PAD;
    int gx = xp + j;
    if constexpr (!EDGE) {
        return xb[(c * HH + gy) * WW + gx];
    } else {
        bool ok = ((unsigned)gy < (unsigned)HH) & ((unsigned)gx < (unsigned)WW);
        int gyc = min(max(gy, 0), HH - 1);
        int gxc = min(max(gx, 0), WW - 1);
        float raw = xb[(c * HH + gyc) * WW + gxc];
        return ok ? raw : 0.f;
    }
}

template<int D0, bool EDGE>
__device__ inline void build_oct_rne(const float* __restrict__ xb, int y, int xp,
                                     float& pn, Oct& b) {
#pragma unroll
    for (int rr = 0; rr < 8; rr += 2) {
        float v0 = xelem<EDGE>(xb, y, xp, D0 + rr);
        float v1 = xelem<EDGE>(xb, y, xp, D0 + rr + 1);
        pn = fmaf(v0, v0, pn);
        pn = fmaf(v1, v1, pn);
        b.w[rr >> 1] = rne_bf16(v0) | (rne_bf16(v1) << 16);   // cvt_pk-able
    }
}

template<int D0>
__device__ inline void build_aoct(const float* __restrict__ wrow, Oct& a) {
#pragma unroll
    for (int rr = 0; rr < 8; rr += 2) {
        float v0 = (D0 + rr     < DD) ? (-2.f * wrow[D0 + rr])     : 0.f;
        float v1 = (D0 + rr + 1 < DD) ? (-2.f * wrow[D0 + rr + 1]) : 0.f;
        a.w[rr >> 1] = rne_bf16(v0) | (rne_bf16(v1) << 16);
    }
}

#define MFMA(A, B, C) __builtin_amdgcn_mfma_f32_32x32x16_bf16((A), (B), (C), 0, 0, 0)

template<bool EDGE>
__device__ inline void do_strip(const float* __restrict__ xb, int y, int xp, int hi,
                                const Oct (&ah)[2][5], float* __restrict__ op) {
    float pnp = 0.f;
    Oct bh[5];
    // Builds are divergent on hi (compile-time D0 differs per half-wave)...
    if (hi == 0) {
        build_oct_rne<0,  EDGE>(xb, y, xp, pnp, bh[0]);
        build_oct_rne<16, EDGE>(xb, y, xp, pnp, bh[1]);
        build_oct_rne<32, EDGE>(xb, y, xp, pnp, bh[2]);
        build_oct_rne<48, EDGE>(xb, y, xp, pnp, bh[3]);
        build_oct_rne<64, EDGE>(xb, y, xp, pnp, bh[4]);
    } else {
        build_oct_rne<8,  EDGE>(xb, y, xp, pnp, bh[0]);
        build_oct_rne<24, EDGE>(xb, y, xp, pnp, bh[1]);
        build_oct_rne<40, EDGE>(xb, y, xp, pnp, bh[2]);
        build_oct_rne<56, EDGE>(xb, y, xp, pnp, bh[3]);
        build_oct_rne<72, EDGE>(xb, y, xp, pnp, bh[4]);   // d75..79 -> 0
    }
    // full ||p||^2: partner half-wave holds the other d's
    float pn = pnp + __shfl_xor(pnp, 32);
    if (hi == 1) {
        // pad slots (elems 3..7 of the hi=1 step-4 octet, d75..79):
        //   B: elem3=1.0, elem4=1.0, elem5=pn_hi, elem6=pn_lo, elem7=0
        unsigned int up  = __builtin_bit_cast(unsigned int, pn);
        float pnhv = __builtin_bit_cast(float, up & 0xFFFF0000u);
        unsigned int pnl = rne_bf16(pn - pnhv);
        bh[4].w[1] |= 0x3F800000u;                  // elem3: 1.0
        bh[4].w[2]  = 0x3F80u | (up & 0xFFFF0000u); // elem4: 1.0, elem5: pn_hi
        bh[4].w[3]  = pnl;                          // elem6: pn_lo, elem7: 0
    }

    // ...MFMAs issue only here, fully re-converged (all lanes' bh valid).
    f32x16 acc0 = {0.f,0.f,0.f,0.f,0.f,0.f,0.f,0.f,0.f,0.f,0.f,0.f,0.f,0.f,0.f,0.f};
    f32x16 acc1 = acc0;
#pragma unroll
    for (int st = 0; st < 5; ++st) {
        acc0 = MFMA(ah[0][st].v, bh[st].v, acc0);
        acc1 = MFMA(ah[1][st].v, bh[st].v, acc1);
    }

    // C/D layout: col = lane&31 (pixel), row = (reg&3)+8*(reg>>2)+4*hi (+32 acc1);
    // the +4*hi is folded into op by the caller.
#pragma unroll
    for (int reg = 0; reg < 16; ++reg) {
        int ob = (reg & 3) + 8 * (reg >> 2);
        op[(size_t)ob * HW]        = sqrtf(fmaxf(acc0[reg], 0.f));
        op[(size_t)(ob + 32) * HW] = sqrtf(fmaxf(acc1[reg], 0.f));
    }
}

__global__ __launch_bounds__(256, 4) void rbf_mfma(const float* __restrict__ x,
                                                   const float* __restrict__ w,
                                                   float* __restrict__ out,
                                                   int nstrips, int nwaves) {
    const int tid  = threadIdx.x;
    const int lane = tid & 63;
    const int l31  = lane & 31;
    const int hi   = lane >> 5;

    // ---- one-time A-fragment + wn build (amortized over ~12 strips) ----
    float wn[2];
#pragma unroll
    for (int mt = 0; mt < 2; ++mt) {
        const float* wrow = w + (l31 + 32 * mt) * DD;
        float s = 0.f;
#pragma unroll 5
        for (int d = 0; d < DD; ++d) { float v = wrow[d]; s = fmaf(v, v, s); }
        wn[mt] = s;
    }
    Oct ah[2][5];
    if (hi == 0) {
#pragma unroll
        for (int mt = 0; mt < 2; ++mt) {
            const float* wrow = w + (l31 + 32 * mt) * DD;
            build_aoct<0 >(wrow, ah[mt][0]);
            build_aoct<16>(wrow, ah[mt][1]);
            build_aoct<32>(wrow, ah[mt][2]);
            build_aoct<48>(wrow, ah[mt][3]);
            build_aoct<64>(wrow, ah[mt][4]);
        }
    } else {
#pragma unroll
        for (int mt = 0; mt < 2; ++mt) {
            const float* wrow = w + (l31 + 32 * mt) * DD;
            build_aoct<8 >(wrow, ah[mt][0]);
            build_aoct<24>(wrow, ah[mt][1]);
            build_aoct<40>(wrow, ah[mt][2]);
            build_aoct<56>(wrow, ah[mt][3]);
            build_aoct<72>(wrow, ah[mt][4]);
            // pad slots: A elem3=wn_hi, elem4=wn_lo, elem5=1.0, elem6=1.0, elem7=0
            unsigned int uwn = __builtin_bit_cast(unsigned int, wn[mt]);
            float wnhv = __builtin_bit_cast(float, uwn & 0xFFFF0000u);
            unsigned int wnl = rne_bf16(wn[mt] - wnhv);
            ah[mt][4].w[1] = (ah[mt][4].w[1] & 0xFFFFu) | (uwn & 0xFFFF0000u);
            ah[mt][4].w[2] = wnl | (0x3F80u << 16);
            ah[mt][4].w[3] = 0x3F80u;
        }
    }

    // ---- strip loop ----
    const int gw = blockIdx.x * 4 + (tid >> 6);
    for (int s = gw; s < nstrips; s += nwaves) {
        int sx = s % NSX;
        int t  = s / NSX;
        int y  = t % HH;
        int b  = t / HH;
        int x0 = sx * 32;
        const float* xb = x + (size_t)b * (CH * HW);
        int xp = x0 + l31 - PAD;
        float* op = out + (size_t)b * OC * HW + (size_t)(y * WW + x0 + l31)
                        + (size_t)hi * 4 * HW;
        bool interior = (y >= PAD) & (y < HH - PAD) & (sx >= 1) & (sx <= 5);
        if (interior) do_strip<false>(xb, y, xp, hi, ah, op);
        else          do_strip<true >(xb, y, xp, hi, ah, op);
    }
}

extern "C" void kernel_launch(void* const* d_in, const int* in_sizes, int n_in,
                              void* d_out, int out_size, void* d_ws, size_t ws_size,
                              hipStream_t stream) {
    const float* x = (const float*)d_in[0];
    const float* w = (const float*)d_in[1];
    float* out     = (float*)d_out;

    int B       = in_sizes[0] / (CH * HW);   // 32
    int nstrips = B * HH * NSX;              // 50176
    int nblocks = 1024;                      // 4 blocks/CU -> 4 waves/SIMD
    int nwaves  = nblocks * 4;

    rbf_mfma<<<nblocks, 256, 0, stream>>>(x, w, out, nstrips, nwaves);
}